// Round 11
// baseline (154.318 us; speedup 1.0000x reference)
//
#include <hip/hip_runtime.h>
#include <cstdint>
#include <cmath>

#define NROWS 8192
#define KDIM  512            // elements; also bytes/row in fp8

typedef int    i32x4  __attribute__((ext_vector_type(4)));
typedef int    i32x8  __attribute__((ext_vector_type(8)));
typedef float  f32x16 __attribute__((ext_vector_type(16)));
typedef unsigned char u8;

#define AS1(p) ((const __attribute__((address_space(1))) void*)(p))
#define AS3(p) ((__attribute__((address_space(3))) void*)(p))

// --- Kernel 1: row L2-normalize fp32 -> fp8 e4m3 (OCP, HW cvt), one wave/row.
// zi rows [0,8192), zj rows [8192,16384). Also zeroes the 128 accumulator slots.
__global__ __launch_bounds__(256) void nrm_kernel(const float* __restrict__ zi,
                                                  const float* __restrict__ zj,
                                                  u8* __restrict__ out,
                                                  double* __restrict__ acc) {
    if (blockIdx.x == 0 && threadIdx.x < 128) acc[threadIdx.x] = 0.0;
    const int wave = threadIdx.x >> 6;
    const int lane = threadIdx.x & 63;
    const int row  = blockIdx.x * 4 + wave;            // 0..16383
    const float* src = (row < NROWS) ? zi + (size_t)row * KDIM
                                     : zj + (size_t)(row - NROWS) * KDIM;
    float4 a = ((const float4*)src)[lane];
    float4 b = ((const float4*)src)[lane + 64];
    float ss = a.x*a.x + a.y*a.y + a.z*a.z + a.w*a.w
             + b.x*b.x + b.y*b.y + b.z*b.z + b.w*b.w;
    #pragma unroll
    for (int off = 32; off >= 1; off >>= 1) ss += __shfl_xor(ss, off, 64);
    const float inv = 1.0f / fmaxf(sqrtf(ss), 1e-12f);
    int p0 = 0, p1 = 0;
    p0 = __builtin_amdgcn_cvt_pk_fp8_f32(a.x * inv, a.y * inv, p0, false);
    p0 = __builtin_amdgcn_cvt_pk_fp8_f32(a.z * inv, a.w * inv, p0, true);
    p1 = __builtin_amdgcn_cvt_pk_fp8_f32(b.x * inv, b.y * inv, p1, false);
    p1 = __builtin_amdgcn_cvt_pk_fp8_f32(b.z * inv, b.w * inv, p1, true);
    int* dst = (int*)(out + (size_t)row * KDIM);
    dst[lane]      = p0;
    dst[lane + 64] = p1;
}

// --- Kernel 2: fused MX-fp8 A*B^T -> exp(10*dot) -> global sum.
// R9 geometry (best known: 84.8 µs): block 256(M)x128(N), 4 waves 2x2, wave tile
// 128x64 = 4x2 frags of 32x32x64, 2 waves/SIMD via __launch_bounds__(256,2).
// R10 change: DOUBLE-BUFFERED LDS, ONE barrier per k-iter (fence-free re-test of
// R4's structure — R4 was confounded by the __threadfence 2.45x slowdown).
// Iter order: issue stage(k+1) -> ds_read frags(k) -> 8 MFMAs -> __syncthreads.
// The barrier's vmcnt(0) drain lands ~700 cyc after stage issue (hidden), vs the
// R9 2-barrier loop that drained ~150 cyc after issue (exposed every iter).
// K-loop fully unrolled so buffer indices are compile-time constants.
// LDS XOR-swizzle (verified R2-R9, absmax 0): region = 32 rows x 64 B; chunk (r,b)
// at p = r*4 + (b ^ ((r>>1)&3)); staging inverse b = (lane&3)^((lane>>3)&3).
// Triangle skip (pos = zi*zi^T symmetric): skip bx<2by; bx>=2by+2 weight 2;
// near-diag pair bx>>1==by at weight 1 with per-element rr==cc skip.
// Pos diagonal added exactly in finalize. Atomics spread over 128 slots.
__global__ __launch_bounds__(256, 2) void gemm_exp_reduce(const u8* __restrict__ A,
                                                          const u8* __restrict__ B,
                                                          double* __restrict__ acc) {
    const int bx = blockIdx.x, by = blockIdx.y;
    const bool pos = (bx < 64);
    if (pos && bx < 2 * by) return;   // strict lower-tri pos block: mirror elsewhere

    __shared__ u8 lA[2][256 * 64];   // 2 x 16 KB = 8 regions (32 rows x 64 k-bytes)
    __shared__ u8 lB[2][128 * 64];   // 2 x 8 KB = 4 regions
    __shared__ float red[4];

    const int tid  = threadIdx.x;
    const int lane = tid & 63;
    const int wave = tid >> 6;
    const int m0   = by * 256;
    const int n0   = bx * 128;
    const int wm   = (wave >> 1) * 128;
    const int wn   = (wave & 1) * 64;

    f32x16 accf[4][2];
    #pragma unroll
    for (int i = 0; i < 4; ++i)
        #pragma unroll
        for (int j = 0; j < 2; ++j)
            #pragma unroll
            for (int r = 0; r < 16; ++r)
                accf[i][j][r] = 0.f;

    // staging (layout verified R2-R9): 16-row chunks of 1024 B. A: wave does
    // chunks wave*4..+3; B: wave*2..+1. lane: global row = chunk*16 + (lane>>2),
    // 16B-col bsw = (lane&3)^((lane>>3)&3); LDS dest = chunk*1024 + lane*16.
    const int bsw = (lane & 3) ^ ((lane >> 3) & 3);
    const u8* gA0 = A + (size_t)(m0 + wave * 64 + (lane >> 2)) * KDIM + bsw * 16;
    const u8* gB0 = B + (size_t)(n0 + wave * 32 + (lane >> 2)) * KDIM + bsw * 16;
    const int ldsA = wave * 4096 + lane * 16;
    const int ldsB = wave * 2048 + lane * 16;

    // fragment read: lane row r=lane&31, k-half q=lane>>5 (16B chunks 2q,2q+1);
    // swizzled position p = r*4 + ((2q) ^ ((r>>1)&3)); partner chunk at ^16.
    const int r_  = lane & 31;
    const int q_  = lane >> 5;
    const int p16 = (r_ * 4 + ((2 * q_) ^ ((r_ >> 1) & 3))) * 16;
    const int aT0 = (wave >> 1) * 4;   // A regions aT0..aT0+3 (128 rows)
    const int bT0 = (wave & 1) * 2;    // B regions bT0..bT0+1 (64 rows)

    // prologue: stage k-block 0 into buffer 0
    #pragma unroll
    for (int c = 0; c < 4; ++c)
        __builtin_amdgcn_global_load_lds(AS1(gA0 + (size_t)c * 16 * KDIM),
                                         AS3(&lA[0][ldsA + c * 1024]), 16, 0, 0);
    #pragma unroll
    for (int c = 0; c < 2; ++c)
        __builtin_amdgcn_global_load_lds(AS1(gB0 + (size_t)c * 16 * KDIM),
                                         AS3(&lB[0][ldsB + c * 1024]), 16, 0, 0);
    __syncthreads();

    #pragma unroll
    for (int kk = 0; kk < 8; ++kk) {
        const int cur = kk & 1;
        const int nxt = cur ^ 1;
        if (kk < 7) {   // stage k-block kk+1; drained at this iter's barrier
            const size_t kb = (size_t)(kk + 1) * 64;
            #pragma unroll
            for (int c = 0; c < 4; ++c)
                __builtin_amdgcn_global_load_lds(AS1(gA0 + kb + (size_t)c * 16 * KDIM),
                                                 AS3(&lA[nxt][ldsA + c * 1024]), 16, 0, 0);
            #pragma unroll
            for (int c = 0; c < 2; ++c)
                __builtin_amdgcn_global_load_lds(AS1(gB0 + kb + (size_t)c * 16 * KDIM),
                                                 AS3(&lB[nxt][ldsB + c * 1024]), 16, 0, 0);
        }

        i32x8 af[4], bfr[2];
        #pragma unroll
        for (int mi = 0; mi < 4; ++mi) {
            const int off = (aT0 + mi) * 2048 + p16;
            *(i32x4*)&af[mi]       = *(const i32x4*)&lA[cur][off];
            *((i32x4*)&af[mi] + 1) = *(const i32x4*)&lA[cur][off ^ 16];
        }
        #pragma unroll
        for (int ni = 0; ni < 2; ++ni) {
            const int off = (bT0 + ni) * 2048 + p16;
            *(i32x4*)&bfr[ni]       = *(const i32x4*)&lB[cur][off];
            *((i32x4*)&bfr[ni] + 1) = *(const i32x4*)&lB[cur][off ^ 16];
        }
        #pragma unroll
        for (int mi = 0; mi < 4; ++mi)
            #pragma unroll
            for (int ni = 0; ni < 2; ++ni)
                accf[mi][ni] = __builtin_amdgcn_mfma_scale_f32_32x32x64_f8f6f4(
                    af[mi], bfr[ni], accf[mi][ni],
                    0, 0,                 // cbsz=fp8(e4m3), blgp=fp8(e4m3)
                    0, 0x7f7f7f7f,        // scale_a: every byte = 2^0
                    0, 0x7f7f7f7f);       // scale_b
        __syncthreads();   // ds_reads of buf[cur] done + buf[nxt] staging drained
    }

    // epilogue: exp(10*d) = exp2(d*10/ln2); near-diag pos blocks skip rr==cc
    const float LOG2E10 = 14.4269504088896341f;
    float part = 0.f;
    if (pos && (bx >> 1) == by) {
        #pragma unroll
        for (int mi = 0; mi < 4; ++mi)
            #pragma unroll
            for (int ni = 0; ni < 2; ++ni)
                #pragma unroll
                for (int r = 0; r < 16; ++r) {
                    // C/D 32x32: col=lane&31, row=(r&3)+8*(r>>2)+4*(lane>>5)
                    int rr = m0 + wm + mi * 32 + ((r & 3) + 8 * (r >> 2) + 4 * q_);
                    int cc = n0 + wn + ni * 32 + r_;
                    if (rr != cc) part += exp2f(accf[mi][ni][r] * LOG2E10);
                }
    } else {
        #pragma unroll
        for (int mi = 0; mi < 4; ++mi)
            #pragma unroll
            for (int ni = 0; ni < 2; ++ni)
                #pragma unroll
                for (int r = 0; r < 16; ++r)
                    part += exp2f(accf[mi][ni][r] * LOG2E10);
    }

    #pragma unroll
    for (int off = 32; off >= 1; off >>= 1) part += __shfl_xor(part, off, 64);
    if (lane == 0) red[wave] = part;
    __syncthreads();
    if (tid == 0) {
        double s = (double)red[0] + (double)red[1] + (double)red[2] + (double)red[3];
        if (pos && bx >= 2 * by + 2) s *= 2.0;   // stands in for its skipped mirror
        atomicAdd(&acc[(pos ? 0 : 64) + (((unsigned)bx * 7 + (unsigned)by) & 63)], s);
    }
}

// --- Kernel 3: loss = log1p(neg/pos), pos += exact diagonal 8192*e^10.
// 128 threads: one global load each (R7-R9's 1-thread loop of 128 L2 loads was
// ~25-30 µs of the total); LDS reduce then scalar finish.
__global__ __launch_bounds__(128) void finalize(const double* __restrict__ acc,
                                                float* __restrict__ out) {
    __shared__ double sp[128];
    const int t = threadIdx.x;
    sp[t] = acc[t];
    __syncthreads();
    if (t == 0) {
        double p = 0.0, n = 0.0;
        #pragma unroll
        for (int i = 0; i < 64; ++i) { p += sp[i]; n += sp[64 + i]; }
        p += 8192.0 * exp(10.0);
        out[0] = (float)log1p(n / p);
    }
}

extern "C" void kernel_launch(void* const* d_in, const int* in_sizes, int n_in,
                              void* d_out, int out_size, void* d_ws, size_t ws_size,
                              hipStream_t stream) {
    const float* zi = (const float*)d_in[0];
    const float* zj = (const float*)d_in[1];
    u8* nrm = (u8*)d_ws;                                      // [16384][512] fp8 = 8 MB
    double* acc = (double*)((char*)d_ws + (size_t)16384 * 512);

    nrm_kernel<<<4096, 256, 0, stream>>>(zi, zj, nrm, acc);
    dim3 grid(128, 32);   // x: 16384/128 n-tiles, y: 8192/256 m-tiles
    gemm_exp_reduce<<<grid, 256, 0, stream>>>(nrm, nrm, acc);
    finalize<<<1, 128, 0, stream>>>(acc, (float*)d_out);
}

// Round 12
// 148.778 us; speedup vs baseline: 1.0372x; 1.0372x over previous
//
#include <hip/hip_runtime.h>
#include <cstdint>
#include <cmath>

#define NROWS 8192
#define KDIM  512            // elements; also bytes/row in fp8

typedef int    i32x4  __attribute__((ext_vector_type(4)));
typedef int    i32x8  __attribute__((ext_vector_type(8)));
typedef float  f32x16 __attribute__((ext_vector_type(16)));
typedef unsigned char u8;

#define AS1(p) ((const __attribute__((address_space(1))) void*)(p))
#define AS3(p) ((__attribute__((address_space(3))) void*)(p))

// --- Kernel 1: row L2-normalize fp32 -> fp8 e4m3 (OCP, HW cvt), one wave/row.
// zi rows [0,8192), zj rows [8192,16384). Also zeroes the 128 accumulator slots.
__global__ __launch_bounds__(256) void nrm_kernel(const float* __restrict__ zi,
                                                  const float* __restrict__ zj,
                                                  u8* __restrict__ out,
                                                  double* __restrict__ acc) {
    if (blockIdx.x == 0 && threadIdx.x < 128) acc[threadIdx.x] = 0.0;
    const int wave = threadIdx.x >> 6;
    const int lane = threadIdx.x & 63;
    const int row  = blockIdx.x * 4 + wave;            // 0..16383
    const float* src = (row < NROWS) ? zi + (size_t)row * KDIM
                                     : zj + (size_t)(row - NROWS) * KDIM;
    float4 a = ((const float4*)src)[lane];
    float4 b = ((const float4*)src)[lane + 64];
    float ss = a.x*a.x + a.y*a.y + a.z*a.z + a.w*a.w
             + b.x*b.x + b.y*b.y + b.z*b.z + b.w*b.w;
    #pragma unroll
    for (int off = 32; off >= 1; off >>= 1) ss += __shfl_xor(ss, off, 64);
    const float inv = 1.0f / fmaxf(sqrtf(ss), 1e-12f);
    int p0 = 0, p1 = 0;
    p0 = __builtin_amdgcn_cvt_pk_fp8_f32(a.x * inv, a.y * inv, p0, false);
    p0 = __builtin_amdgcn_cvt_pk_fp8_f32(a.z * inv, a.w * inv, p0, true);
    p1 = __builtin_amdgcn_cvt_pk_fp8_f32(b.x * inv, b.y * inv, p1, false);
    p1 = __builtin_amdgcn_cvt_pk_fp8_f32(b.z * inv, b.w * inv, p1, true);
    int* dst = (int*)(out + (size_t)row * KDIM);
    dst[lane]      = p0;
    dst[lane + 64] = p1;
}

// --- Kernel 2: fused MX-fp8 A*B^T -> exp(10*dot) -> global sum.
// R9 geometry (best known: 84.8 µs): block 256(M)x128(N), 4 waves 2x2, wave tile
// 128x64 = 4x2 frags of 32x32x64, single-buffer LDS, 2-barrier K-loop, no fence.
// R11 change: BK=128 — stage TWO 64-B k-slices per iter, run two inner k-halves
// (16 MFMAs/wave) between barrier pairs. Halves barrier events 16 -> 8 per block
// (each barrier = vmcnt(0) drain + 8-wave convergence, the measured ~9% + stall
// driver). Single-buffer 48 KB LDS keeps >=3 blocks/CU by LDS (m132's BK=128
// failure was dbuf/64KB occupancy loss — avoided). R10's dbuf regressed: reverted.
// LDS XOR-swizzle (verified R2-R10, absmax 0): region = 32 rows x 64 B; chunk
// (r,b) at p = r*4 + (b ^ ((r>>1)&3)); staging inverse b = (lane&3)^((lane>>3)&3).
// Triangle skip (pos = zi*zi^T symmetric): skip bx<2by; bx>=2by+2 weight 2;
// near-diag pair bx>>1==by at weight 1 with per-element rr==cc skip.
// Pos diagonal added exactly in finalize. Atomics spread over 128 slots.
__global__ __launch_bounds__(256, 2) void gemm_exp_reduce(const u8* __restrict__ A,
                                                          const u8* __restrict__ B,
                                                          double* __restrict__ acc) {
    const int bx = blockIdx.x, by = blockIdx.y;
    const bool pos = (bx < 64);
    if (pos && bx < 2 * by) return;   // strict lower-tri pos block: mirror elsewhere

    __shared__ u8 lA[2][256 * 64];   // 2 k-halves x 16 KB (8 regions of 32r x 64B)
    __shared__ u8 lB[2][128 * 64];   // 2 k-halves x 8 KB  (4 regions)
    __shared__ float red[4];

    const int tid  = threadIdx.x;
    const int lane = tid & 63;
    const int wave = tid >> 6;
    const int m0   = by * 256;
    const int n0   = bx * 128;
    const int wm   = (wave >> 1) * 128;
    const int wn   = (wave & 1) * 64;

    f32x16 accf[4][2];
    #pragma unroll
    for (int i = 0; i < 4; ++i)
        #pragma unroll
        for (int j = 0; j < 2; ++j)
            #pragma unroll
            for (int r = 0; r < 16; ++r)
                accf[i][j][r] = 0.f;

    // staging (layout verified R2-R10): 16-row chunks of 1024 B per k-half.
    // A: wave does chunks wave*4..+3 (both halves); B: wave*2..+1.
    // lane: global row = chunk*16 + (lane>>2), 16B-col bsw = (lane&3)^((lane>>3)&3).
    const int bsw = (lane & 3) ^ ((lane >> 3) & 3);
    const u8* gA0 = A + (size_t)(m0 + wave * 64 + (lane >> 2)) * KDIM + bsw * 16;
    const u8* gB0 = B + (size_t)(n0 + wave * 32 + (lane >> 2)) * KDIM + bsw * 16;
    const int ldsA = wave * 4096 + lane * 16;
    const int ldsB = wave * 2048 + lane * 16;

    // fragment read: lane row r=lane&31, k-half-of-64 q=lane>>5 (chunks 2q,2q+1);
    // swizzled position p = r*4 + ((2q) ^ ((r>>1)&3)); partner chunk at ^16.
    const int r_  = lane & 31;
    const int q_  = lane >> 5;
    const int p16 = (r_ * 4 + ((2 * q_) ^ ((r_ >> 1) & 3))) * 16;
    const int aT0 = (wave >> 1) * 4;   // A regions aT0..aT0+3 (128 rows)
    const int bT0 = (wave & 1) * 2;    // B regions bT0..bT0+1 (64 rows)

    for (int k0 = 0; k0 < KDIM; k0 += 128) {   // BK=128: 4 iters, 8 barriers total
        __syncthreads();   // previous iteration's ds_reads done before overwrite
        #pragma unroll
        for (int h = 0; h < 2; ++h) {
            const size_t kb = (size_t)k0 + h * 64;
            #pragma unroll
            for (int c = 0; c < 4; ++c)
                __builtin_amdgcn_global_load_lds(AS1(gA0 + kb + (size_t)c * 16 * KDIM),
                                                 AS3(&lA[h][ldsA + c * 1024]), 16, 0, 0);
            #pragma unroll
            for (int c = 0; c < 2; ++c)
                __builtin_amdgcn_global_load_lds(AS1(gB0 + kb + (size_t)c * 16 * KDIM),
                                                 AS3(&lB[h][ldsB + c * 1024]), 16, 0, 0);
        }
        __syncthreads();   // vmcnt drain + barrier: both k-halves ready

        #pragma unroll
        for (int h = 0; h < 2; ++h) {   // 16 MFMAs between barrier pairs
            i32x8 af[4], bfr[2];
            #pragma unroll
            for (int mi = 0; mi < 4; ++mi) {
                const int off = (aT0 + mi) * 2048 + p16;
                *(i32x4*)&af[mi]       = *(const i32x4*)&lA[h][off];
                *((i32x4*)&af[mi] + 1) = *(const i32x4*)&lA[h][off ^ 16];
            }
            #pragma unroll
            for (int ni = 0; ni < 2; ++ni) {
                const int off = (bT0 + ni) * 2048 + p16;
                *(i32x4*)&bfr[ni]       = *(const i32x4*)&lB[h][off];
                *((i32x4*)&bfr[ni] + 1) = *(const i32x4*)&lB[h][off ^ 16];
            }
            #pragma unroll
            for (int mi = 0; mi < 4; ++mi)
                #pragma unroll
                for (int ni = 0; ni < 2; ++ni)
                    accf[mi][ni] = __builtin_amdgcn_mfma_scale_f32_32x32x64_f8f6f4(
                        af[mi], bfr[ni], accf[mi][ni],
                        0, 0,                 // cbsz=fp8(e4m3), blgp=fp8(e4m3)
                        0, 0x7f7f7f7f,        // scale_a: every byte = 2^0
                        0, 0x7f7f7f7f);       // scale_b
        }
    }

    // epilogue: exp(10*d) = exp2(d*10/ln2); near-diag pos blocks skip rr==cc
    const float LOG2E10 = 14.4269504088896341f;
    float part = 0.f;
    if (pos && (bx >> 1) == by) {
        #pragma unroll
        for (int mi = 0; mi < 4; ++mi)
            #pragma unroll
            for (int ni = 0; ni < 2; ++ni)
                #pragma unroll
                for (int r = 0; r < 16; ++r) {
                    // C/D 32x32: col=lane&31, row=(r&3)+8*(r>>2)+4*(lane>>5)
                    int rr = m0 + wm + mi * 32 + ((r & 3) + 8 * (r >> 2) + 4 * q_);
                    int cc = n0 + wn + ni * 32 + r_;
                    if (rr != cc) part += exp2f(accf[mi][ni][r] * LOG2E10);
                }
    } else {
        #pragma unroll
        for (int mi = 0; mi < 4; ++mi)
            #pragma unroll
            for (int ni = 0; ni < 2; ++ni)
                #pragma unroll
                for (int r = 0; r < 16; ++r)
                    part += exp2f(accf[mi][ni][r] * LOG2E10);
    }

    #pragma unroll
    for (int off = 32; off >= 1; off >>= 1) part += __shfl_xor(part, off, 64);
    if (lane == 0) red[wave] = part;
    __syncthreads();
    if (tid == 0) {
        double s = (double)red[0] + (double)red[1] + (double)red[2] + (double)red[3];
        if (pos && bx >= 2 * by + 2) s *= 2.0;   // stands in for its skipped mirror
        atomicAdd(&acc[(pos ? 0 : 64) + (((unsigned)bx * 7 + (unsigned)by) & 63)], s);
    }
}

// --- Kernel 3: loss = log1p(neg/pos), pos += exact diagonal 8192*e^10.
// 128 threads, one global load each; LDS reduce then scalar finish.
__global__ __launch_bounds__(128) void finalize(const double* __restrict__ acc,
                                                float* __restrict__ out) {
    __shared__ double sp[128];
    const int t = threadIdx.x;
    sp[t] = acc[t];
    __syncthreads();
    if (t == 0) {
        double p = 0.0, n = 0.0;
        #pragma unroll
        for (int i = 0; i < 64; ++i) { p += sp[i]; n += sp[64 + i]; }
        p += 8192.0 * exp(10.0);
        out[0] = (float)log1p(n / p);
    }
}

extern "C" void kernel_launch(void* const* d_in, const int* in_sizes, int n_in,
                              void* d_out, int out_size, void* d_ws, size_t ws_size,
                              hipStream_t stream) {
    const float* zi = (const float*)d_in[0];
    const float* zj = (const float*)d_in[1];
    u8* nrm = (u8*)d_ws;                                      // [16384][512] fp8 = 8 MB
    double* acc = (double*)((char*)d_ws + (size_t)16384 * 512);

    nrm_kernel<<<4096, 256, 0, stream>>>(zi, zj, nrm, acc);
    dim3 grid(128, 32);   // x: 16384/128 n-tiles, y: 8192/256 m-tiles
    gemm_exp_reduce<<<grid, 256, 0, stream>>>(nrm, nrm, acc);
    finalize<<<1, 128, 0, stream>>>(acc, (float*)d_out);
}